// Round 1
// baseline (161.693 us; speedup 1.0000x reference)
//
#include <hip/hip_runtime.h>
#include <hip/hip_bf16.h>

#define LL 197
#define NN 128
#define DD 768
#define TT 16
#define PP 196
#define NO 980   // 5 * 196

static __device__ __forceinline__ ushort f2bf(float f) {
    union { float f; unsigned int u; } a; a.f = f;
    unsigned int r = a.u + 0x7fffu + ((a.u >> 16) & 1u);
    return (ushort)(r >> 16);
}
static __device__ __forceinline__ float bflo(unsigned int u) {
    union { unsigned int u; float f; } c; c.u = u << 16; return c.f;
}
static __device__ __forceinline__ float bfhi(unsigned int u) {
    union { unsigned int u; float f; } c; c.u = u & 0xffff0000u; return c.f;
}

// K1: LayerNorm, one 64-lane wave per row of D=768. fp32 in, bf16 out.
__global__ __launch_bounds__(256) void k_ln(const float* __restrict__ x,
                                            const float* __restrict__ gamma,
                                            const float* __restrict__ beta,
                                            ushort* __restrict__ xn) {
    int row  = (blockIdx.x << 2) + (threadIdx.x >> 6);
    int lane = threadIdx.x & 63;
    if (row >= LL * NN) return;
    const float4* xr = (const float4*)(x + (size_t)row * DD);
    float4 v[3];
    float s = 0.f, ss = 0.f;
#pragma unroll
    for (int j = 0; j < 3; ++j) {
        v[j] = xr[lane + 64 * j];
        s  += v[j].x + v[j].y + v[j].z + v[j].w;
        ss += v[j].x * v[j].x + v[j].y * v[j].y + v[j].z * v[j].z + v[j].w * v[j].w;
    }
#pragma unroll
    for (int o = 32; o > 0; o >>= 1) { s += __shfl_xor(s, o); ss += __shfl_xor(ss, o); }
    float mu  = s * (1.f / DD);
    float var = ss * (1.f / DD) - mu * mu;
    float rs  = rsqrtf(var + 1e-5f);
    ushort4* outr = (ushort4*)(xn + (size_t)row * DD);
    const float4* g4 = (const float4*)gamma;
    const float4* b4 = (const float4*)beta;
#pragma unroll
    for (int j = 0; j < 3; ++j) {
        int i4 = lane + 64 * j;
        float4 g = g4[i4], b = b4[i4];
        ushort4 o4;
        o4.x = f2bf((v[j].x - mu) * rs * g.x + b.x);
        o4.y = f2bf((v[j].y - mu) * rs * g.y + b.y);
        o4.z = f2bf((v[j].z - mu) * rs * g.z + b.z);
        o4.w = f2bf((v[j].w - mu) * rs * g.w + b.w);
        outr[i4] = o4;
    }
}

// K2: aff weights. One wave per (n, o) dot product, 4 o-chunks per n.
// wtab[n][o] = sigmoid(q_n . v_{o,n} / sqrt(D)) - 0.5, or 0 if neighbor OOR.
__global__ __launch_bounds__(256) void k_aff(const ushort* __restrict__ xn,
                                             float* __restrict__ wtab) {
    int n     = blockIdx.x >> 2;
    int chunk = blockIdx.x & 3;
    int wid   = threadIdx.x >> 6;
    int lane  = threadIdx.x & 63;
    int b = n >> 4, t = n & 15;
    const unsigned int* qrow = (const unsigned int*)(xn + (size_t)n * DD);
    float q0[6], q1[6];
#pragma unroll
    for (int k = 0; k < 6; ++k) {
        unsigned int u = qrow[lane + 64 * k];
        q0[k] = bflo(u); q1[k] = bfhi(u);
    }
    int o_end = chunk * 245 + 245;
    for (int o = chunk * 245 + wid; o < o_end; o += 4) {
        int w5 = o / PP;
        int p  = o - w5 * PP;
        int m  = t + w5 - 2;
        float res = 0.f;
        if (m >= 0 && m < TT) {
            const unsigned int* xrow =
                (const unsigned int*)(xn + ((size_t)(1 + p) * NN + (b * TT + m)) * DD);
            float acc = 0.f;
#pragma unroll
            for (int k = 0; k < 6; ++k) {
                unsigned int u = xrow[lane + 64 * k];
                acc = fmaf(q0[k], bflo(u), acc);
                acc = fmaf(q1[k], bfhi(u), acc);
            }
#pragma unroll
            for (int d = 32; d > 0; d >>= 1) acc += __shfl_xor(acc, d);
            float sv = acc * 0.03608439182435161f;   // 1/sqrt(768)
            res = 1.f / (1.f + __expf(-sv)) - 0.5f;
        }
        if (lane == 0) wtab[n * NO + o] = res;
    }
}

// K3: feat[n][d] = sum_o wtab[n][o] * v_{o,n}[d]; partial over o-chunk, atomicAdd.
__global__ __launch_bounds__(384) void k_feat(const ushort* __restrict__ xn,
                                              const float* __restrict__ wtab,
                                              float* __restrict__ out) {
    int n     = blockIdx.x >> 2;
    int chunk = blockIdx.x & 3;
    int b = n >> 4, t = n & 15;
    int d2 = threadIdx.x;                 // bf16-pair index, 0..383
    float a0 = 0.f, a1 = 0.f;
    int o0 = chunk * 245;
#pragma unroll 4
    for (int o = o0; o < o0 + 245; ++o) {
        int w5 = o / PP;
        int p  = o - w5 * PP;
        int m  = t + w5 - 2;
        if (m < 0 || m >= TT) continue;   // wtab is 0 there anyway
        float wv = wtab[n * NO + o];
        unsigned int u =
            ((const unsigned int*)(xn + ((size_t)(1 + p) * NN + (b * TT + m)) * DD))[d2];
        a0 = fmaf(wv, bflo(u), a0);
        a1 = fmaf(wv, bfhi(u), a1);
    }
    float* dst = out + (size_t)n * DD + d2 * 2;
    atomicAdd(dst, a0);
    atomicAdd(dst + 1, a1);
}

extern "C" void kernel_launch(void* const* d_in, const int* in_sizes, int n_in,
                              void* d_out, int out_size, void* d_ws, size_t ws_size,
                              hipStream_t stream) {
    const float* x     = (const float*)d_in[0];
    const float* gamma = (const float*)d_in[1];
    const float* beta  = (const float*)d_in[2];
    float* out = (float*)d_out;
    ushort* xn = (ushort*)d_ws;                                   // 197*128*768 bf16 = 38.7 MB
    float* wtab = (float*)((char*)d_ws + (size_t)LL * NN * DD * 2); // 128*980 fp32

    hipMemsetAsync(d_out, 0, (size_t)NN * DD * sizeof(float), stream);
    k_ln  <<<(LL * NN + 3) / 4, 256, 0, stream>>>(x, gamma, beta, xn);
    k_aff <<<NN * 4, 256, 0, stream>>>(xn, wtab);
    k_feat<<<NN * 4, 384, 0, stream>>>(xn, wtab, out);
}

// Round 2
// 51.527 us; speedup vs baseline: 3.1381x; 3.1381x over previous
//
#include <hip/hip_runtime.h>

#define LL 197
#define NN 128
#define DD 768
#define TT 16
#define PP 196

static __device__ __forceinline__ float wave_sum(float v) {
#pragma unroll
    for (int o = 32; o > 0; o >>= 1) v += __shfl_xor(v, o);
    return v;
}

// LayerNorm a 768-float row held as 3 float4/lane (lane-strided layout:
// float4 index = lane + 64k). Produces 12 normalized floats per lane.
static __device__ __forceinline__ void ln_row(const float4* c, const float4* gv,
                                              const float4* bv, float* v) {
    float s = 0.f, ss = 0.f;
#pragma unroll
    for (int k = 0; k < 3; ++k) {
        s += c[k].x + c[k].y + c[k].z + c[k].w;
        ss = fmaf(c[k].x, c[k].x, ss);
        ss = fmaf(c[k].y, c[k].y, ss);
        ss = fmaf(c[k].z, c[k].z, ss);
        ss = fmaf(c[k].w, c[k].w, ss);
    }
    s = wave_sum(s);
    ss = wave_sum(ss);
    float mu  = s * (1.f / 768.f);
    float var = fmaf(ss, 1.f / 768.f, -mu * mu);
    float rs  = rsqrtf(var + 1e-5f);
    float nmr = -mu * rs;
#pragma unroll
    for (int k = 0; k < 3; ++k) {
        v[4 * k + 0] = fmaf(fmaf(c[k].x, rs, nmr), gv[k].x, bv[k].x);
        v[4 * k + 1] = fmaf(fmaf(c[k].y, rs, nmr), gv[k].y, bv[k].y);
        v[4 * k + 2] = fmaf(fmaf(c[k].z, rs, nmr), gv[k].z, bv[k].z);
        v[4 * k + 3] = fmaf(fmaf(c[k].w, rs, nmr), gv[k].w, bv[k].w);
    }
}

// One block per (b, m, chunk). Streams value rows x[1+p, b*16+m, :] once,
// LNs them in-wave, forms the 5 sigmoid weights against the 5 LN'd cls
// queries (t = m-2..m+2), accumulates weighted rows, combines via LDS,
// atomicAdds into out.
__global__ __launch_bounds__(256, 2) void k_fused(const float* __restrict__ x,
                                                  const float* __restrict__ gamma,
                                                  const float* __restrict__ beta,
                                                  float* __restrict__ out) {
    __shared__ float ls[4 * 3840];
    int gid   = blockIdx.x;        // 0..511
    int bm    = gid >> 2;          // value-row n index = b*16+m
    int chunk = gid & 3;
    int b = bm >> 4, m = bm & 15;
    int wid = threadIdx.x >> 6, lane = threadIdx.x & 63;

    const float4* g4 = (const float4*)gamma;
    const float4* b4 = (const float4*)beta;
    float4 gv[3], bv[3];
#pragma unroll
    for (int k = 0; k < 3; ++k) { gv[k] = g4[lane + 64 * k]; bv[k] = b4[lane + 64 * k]; }

    // LN'd queries: q_j = LN(x[0, b*16+(m-2+j), :])
    float q[5][12];
#pragma unroll
    for (int j = 0; j < 5; ++j) {
        int t = m - 2 + j;
        if (t >= 0 && t < TT) {
            const float4* qr = (const float4*)(x + (size_t)(b * TT + t) * DD);
            float4 c[3];
#pragma unroll
            for (int k = 0; k < 3; ++k) c[k] = qr[lane + 64 * k];
            ln_row(c, gv, bv, q[j]);
        } else {
#pragma unroll
            for (int i = 0; i < 12; ++i) q[j][i] = 0.f;
        }
    }

    float acc[60];
#pragma unroll
    for (int i = 0; i < 60; ++i) acc[i] = 0.f;

    const size_t pstride = (size_t)16 * NN * DD;   // p advances by 16
    int p = chunk * 4 + wid;                        // 0..15
    const float* vrow = x + (size_t)(1 + p) * NN * DD + (size_t)bm * DD;

    float4 cur[3], nxt[3];
    if (p < PP) {
        const float4* rp = (const float4*)vrow;
#pragma unroll
        for (int k = 0; k < 3; ++k) cur[k] = rp[lane + 64 * k];
    }
    while (p < PP) {
        int pn = p + 16;
        const float* vrow_n = vrow + pstride;
        if (pn < PP) {
            const float4* rp = (const float4*)vrow_n;
#pragma unroll
            for (int k = 0; k < 3; ++k) nxt[k] = rp[lane + 64 * k];
        }
        float v[12];
        ln_row(cur, gv, bv, v);

        float d0 = 0.f, d1 = 0.f, d2 = 0.f, d3 = 0.f, d4 = 0.f;
#pragma unroll
        for (int k = 0; k < 12; ++k) {
            d0 = fmaf(q[0][k], v[k], d0);
            d1 = fmaf(q[1][k], v[k], d1);
            d2 = fmaf(q[2][k], v[k], d2);
            d3 = fmaf(q[3][k], v[k], d3);
            d4 = fmaf(q[4][k], v[k], d4);
        }
#pragma unroll
        for (int o = 32; o > 0; o >>= 1) {
            d0 += __shfl_xor(d0, o);
            d1 += __shfl_xor(d1, o);
            d2 += __shfl_xor(d2, o);
            d3 += __shfl_xor(d3, o);
            d4 += __shfl_xor(d4, o);
        }
        const float scl = 0.03608439182435161f;    // 1/sqrt(768)
        float w[5];
        w[0] = __builtin_amdgcn_rcpf(1.f + __expf(-d0 * scl)) - 0.5f;
        w[1] = __builtin_amdgcn_rcpf(1.f + __expf(-d1 * scl)) - 0.5f;
        w[2] = __builtin_amdgcn_rcpf(1.f + __expf(-d2 * scl)) - 0.5f;
        w[3] = __builtin_amdgcn_rcpf(1.f + __expf(-d3 * scl)) - 0.5f;
        w[4] = __builtin_amdgcn_rcpf(1.f + __expf(-d4 * scl)) - 0.5f;
#pragma unroll
        for (int j = 0; j < 5; ++j)
#pragma unroll
            for (int k = 0; k < 12; ++k) acc[j * 12 + k] = fmaf(w[j], v[k], acc[j * 12 + k]);

#pragma unroll
        for (int k = 0; k < 3; ++k) cur[k] = nxt[k];
        vrow = vrow_n;
        p = pn;
    }

    // Wave regions in LDS: region wid, layout j*768 + d (d = 256k + 4*lane).
    float* lw = ls + wid * 3840;
#pragma unroll
    for (int j = 0; j < 5; ++j)
#pragma unroll
        for (int k = 0; k < 3; ++k) {
            float4 t4;
            t4.x = acc[j * 12 + 4 * k + 0];
            t4.y = acc[j * 12 + 4 * k + 1];
            t4.z = acc[j * 12 + 4 * k + 2];
            t4.w = acc[j * 12 + 4 * k + 3];
            *(float4*)(lw + j * 768 + 256 * k + 4 * lane) = t4;
        }
    __syncthreads();

    const float4* ls4 = (const float4*)ls;
    for (int idx = threadIdx.x; idx < 960; idx += 256) {
        int j = idx / 192;
        int t = m - 2 + j;
        if (t < 0 || t >= TT) continue;
        float4 a0 = ls4[idx];
        float4 a1 = ls4[960 + idx];
        float4 a2 = ls4[1920 + idx];
        float4 a3 = ls4[2880 + idx];
        float sx = a0.x + a1.x + a2.x + a3.x;
        float sy = a0.y + a1.y + a2.y + a3.y;
        float sz = a0.z + a1.z + a2.z + a3.z;
        float sw = a0.w + a1.w + a2.w + a3.w;
        int d = (idx - j * 192) * 4;
        float* dst = out + (size_t)(b * TT + t) * DD + d;
        atomicAdd(dst + 0, sx);
        atomicAdd(dst + 1, sy);
        atomicAdd(dst + 2, sz);
        atomicAdd(dst + 3, sw);
    }
}

extern "C" void kernel_launch(void* const* d_in, const int* in_sizes, int n_in,
                              void* d_out, int out_size, void* d_ws, size_t ws_size,
                              hipStream_t stream) {
    const float* x     = (const float*)d_in[0];
    const float* gamma = (const float*)d_in[1];
    const float* beta  = (const float*)d_in[2];
    float* out = (float*)d_out;

    hipMemsetAsync(d_out, 0, (size_t)NN * DD * sizeof(float), stream);
    k_fused<<<NN * 4, 256, 0, stream>>>(x, gamma, beta, out);
}